// Round 2
// 575.748 us; speedup vs baseline: 1.0426x; 1.0426x over previous
//
#include <hip/hip_runtime.h>

// Fused LocalSelfAttention (Swin windows ws=8, nh=16, hd=32), B=16 N=4096 C=512.
// v2b: head-per-wave-pair restructure (v2 resubmit + __align__(16) on LDS
// arrays — ushort __shared__ only guarantees 2B alignment; all vector LDS
// accesses (b64/b128) need 16B base alignment or they fault).
//   - waves w and w+4 (same SIMD) co-own head h = pass*4 + (w&3), split by
//     token half (mh = w>>2). GEMM1 is output-stationary per head: per kk-step
//     2 A-frags + 6 B-frags -> 12 MFMA (vs 7 loads : 6 MFMA before), weight
//     streams disjoint per pair (pair-sharing gives L1 hits).
//   - attention in per-pair private LDS scratch, S^T = K.Q^T layout so the
//     softmax key-reduction is in-lane (15 fmax + 2 shfl per row group);
//     1/sum deferred to O-scale. No block barriers inside attention.
//   - proj fused as K-chunks (K-tile == head): ob is a 16KB overlay in scr,
//     proj accumulator in registers across the 4 passes.
//   - barriers 26 -> 17; proj(p) overlaps GEMM1(p+1). LDS 155K -> 114K.

typedef short s16x8 __attribute__((ext_vector_type(8)));
typedef float f32x4 __attribute__((ext_vector_type(4)));

union V8 { uint4 u4; uint2 u2[2]; s16x8 h; ushort s[8]; uint u[4]; };

__device__ __forceinline__ ushort f2b(float f) {
    union { float f; uint u; } v; v.f = f;
    return (ushort)((v.u + 0x7fffu + ((v.u >> 16) & 1u)) >> 16);  // RNE
}
// 8 fp32 -> 8 bf16 truncation (1 v_perm per pair)
__device__ __forceinline__ void cvt8(const float* __restrict__ p, V8& d) {
    union { float4 f; uint u[4]; } a, b;
    a.f = *(const float4*)p;  b.f = *(const float4*)(p + 4);
    d.u[0] = __builtin_amdgcn_perm(a.u[1], a.u[0], 0x07060302u);
    d.u[1] = __builtin_amdgcn_perm(a.u[3], a.u[2], 0x07060302u);
    d.u[2] = __builtin_amdgcn_perm(b.u[1], b.u[0], 0x07060302u);
    d.u[3] = __builtin_amdgcn_perm(b.u[3], b.u[2], 0x07060302u);
}
__device__ __forceinline__ f32x4 mfma16(s16x8 a, s16x8 b, f32x4 c) {
    return __builtin_amdgcn_mfma_f32_16x16x32_bf16(a, b, c, 0, 0, 0);
}
__device__ __forceinline__ uint2 pack4(float a, float b, float c, float d) {
    uint2 r;
    r.x = (uint)f2b(a) | ((uint)f2b(b) << 16);
    r.y = (uint)f2b(c) | ((uint)f2b(d) << 16);
    return r;
}

// ---------------------------------------------------------------------------
// Prologue: fp32 weights -> bf16 in MFMA-fragment order.
// qkv: tiles 0..95 (mat*32 + ntile) at ws[0..786432); proj: tiles 0..31 at
// ws[786432..1048576). Per (tile,kk): 512-short block, element
// (quad*128 + colw*8 + j) = w[n=tile*16+colw][k=kk*32+quad*8+j].
// ---------------------------------------------------------------------------
__global__ __launch_bounds__(256)
void pack_w(const float* __restrict__ wqkv, const float* __restrict__ wproj,
            ushort* __restrict__ dst)
{
    const int gid = blockIdx.x * 256 + threadIdx.x;   // 131072 threads
    const int o = gid << 3;                           // short index in dst
    const int colw = (o >> 3) & 15, quad = (o >> 7) & 3, kk = (o >> 9) & 15;
    const int tile = o >> 13;
    const float* src;
    if (o < 786432) {
        const int mat = tile >> 5, nt = tile & 31;
        src = wqkv + (size_t)(mat * 512 + nt * 16 + colw) * 512 + (kk << 5) + (quad << 3);
    } else {
        const int nt = tile - 96;
        src = wproj + (size_t)(nt * 16 + colw) * 512 + (kk << 5) + (quad << 3);
    }
    float4 a = *(const float4*)src, b = *(const float4*)(src + 4);
    V8 v;
    v.s[0] = f2b(a.x); v.s[1] = f2b(a.y); v.s[2] = f2b(a.z); v.s[3] = f2b(a.w);
    v.s[4] = f2b(b.x); v.s[5] = f2b(b.y); v.s[6] = f2b(b.z); v.s[7] = f2b(b.w);
    *(uint4*)(dst + o) = v.u4;
}

// ---------------------------------------------------------------------------
// Fused kernel. PK=true: packed bf16 weights in ws. PK=false: fp32 fallback.
// ---------------------------------------------------------------------------
template<bool PK>
__global__ __launch_bounds__(512, 2)
void win_fused(const float* __restrict__ x, const void* __restrict__ Wq,
               const void* __restrict__ Wp, const float* __restrict__ bproj,
               float* __restrict__ out)
{
    __shared__ __align__(16) ushort xw[64 * 512];  // window A-tile (bf16, swizzled) 64K
    __shared__ __align__(16) ushort scr[4][6400];  // per-pair scratch; ob overlay 50K

    const int tid  = threadIdx.x;
    const int lane = tid & 63;
    const int wave = tid >> 6;           // 0..7
    const int pid  = wave & 3;           // pair id (head within pass)
    const int mh   = wave >> 2;          // token half 0/1
    const int col  = lane & 15, quad = lane >> 4;
    const int win  = blockIdx.x;
    const int bb = win >> 6, wh = (win >> 3) & 7, ww = win & 7;
    const size_t xbase = (size_t)(bb * 4096) * 512;

    // ---------------- gather (scrambled window partition), fp32 -> bf16 ------
    {
        const int m8  = tid & 63;
        const int u8  = tid >> 6;                       // spatial row-in-window
        const int t   = ((m8 & 7) << 3) | (m8 >> 3);
        const int ch0 = m8 << 3;
        const float* gp = x + xbase + (size_t)(wh * 512 + u8 * 64 + ww * 8) * 512 + ch0;
        V8 L[8];
        #pragma unroll
        for (int du = 0; du < 8; ++du) cvt8(gp + du * 512, L[du]);
        #pragma unroll
        for (int e = 0; e < 8; ++e) {
            V8 W;
            #pragma unroll
            for (int du = 0; du < 8; ++du) W.s[du] = L[du].s[e];
            const int c8 = (e << 3) | u8;
            *(uint4*)(&xw[(t << 9) + ((c8 ^ (t & 7)) << 3)]) = W.u4;
        }
    }
    __syncthreads();

    // per-pair scratch regions (shorts): q [0,2080) stride 520/g; k [2080,4160);
    // vT [4160,6272) stride 264/gg. P overlays q (own token-slots only).
    ushort* const hs = &scr[pid][0];
    ushort* const ob = &scr[0][0];       // per-pass o tile: 64 tok x 128 ch, 8192 shorts
    constexpr int QOFF = 0, KOFF = 2080, VTOFF = 4160;

    f32x4 pacc[2][8];                    // proj accumulator: 2 m-tiles x 8 n-tiles
    #pragma unroll
    for (int mt = 0; mt < 2; ++mt)
        #pragma unroll
        for (int nt = 0; nt < 8; ++nt) pacc[mt][nt] = (f32x4){0.f, 0.f, 0.f, 0.f};

    for (int p = 0; p < 4; ++p) {
        const int h = (p << 2) | pid;    // head handled by this pair

        // ---- GEMM1: q,k,v for head h, this wave's 32-token half, K=512 ----
        f32x4 cq[2][2], ck[2][2], cv[2][2];
        #pragma unroll
        for (int mt = 0; mt < 2; ++mt)
            #pragma unroll
            for (int nt = 0; nt < 2; ++nt) {
                cq[mt][nt] = (f32x4){0.f, 0.f, 0.f, 0.f};
                ck[mt][nt] = (f32x4){0.f, 0.f, 0.f, 0.f};
                cv[mt][nt] = (f32x4){0.f, 0.f, 0.f, 0.f};
            }
        #pragma unroll 2
        for (int kk = 0; kk < 16; ++kk) {
            s16x8 a[2];
            #pragma unroll
            for (int mt = 0; mt < 2; ++mt) {
                const int t = mh * 32 + (mt << 4) + col;
                const int c8 = (kk << 2) | quad;
                V8 v; v.u4 = *(const uint4*)(&xw[(t << 9) + ((c8 ^ (t & 7)) << 3)]);
                a[mt] = v.h;
            }
            #pragma unroll
            for (int nt = 0; nt < 2; ++nt) {
                s16x8 bq, bk, bv;
                if constexpr (PK) {
                    const ushort* W = (const ushort*)Wq;
                    const size_t base = ((size_t)(((h << 1) | nt) << 4) + kk) * 512 + (lane << 3);
                    V8 q_, k_, v_;
                    q_.u4 = *(const uint4*)(&W[base]);
                    k_.u4 = *(const uint4*)(&W[base + 262144]);
                    v_.u4 = *(const uint4*)(&W[base + 524288]);
                    bq = q_.h; bk = k_.h; bv = v_.h;
                } else {
                    const float* W = (const float*)Wq;
                    const float* wp = W + (size_t)((h << 5) + (nt << 4) + col) * 512 + (kk << 5) + (quad << 3);
                    V8 q_, k_, v_;
                    cvt8(wp, q_); cvt8(wp + 512 * 512, k_); cvt8(wp + 1024 * 512, v_);
                    bq = q_.h; bk = k_.h; bv = v_.h;
                }
                #pragma unroll
                for (int mt = 0; mt < 2; ++mt) {
                    cq[mt][nt] = mfma16(a[mt], bq, cq[mt][nt]);
                    ck[mt][nt] = mfma16(a[mt], bk, ck[mt][nt]);
                    cv[mt][nt] = mfma16(a[mt], bv, cv[mt][nt]);
                }
            }
        }

        __syncthreads();   // BAR(a): prior proj reads of scr/ob done before stores

        // ---- q,k (scalar transpose) + vT (packed b64) -> pair scratch ----
        #pragma unroll
        for (int mt = 0; mt < 2; ++mt)
            #pragma unroll
            for (int nt = 0; nt < 2; ++nt) {
                const int c = (nt << 4) + col;             // ch 0..31
                #pragma unroll
                for (int r = 0; r < 4; ++r) {
                    const int t = mh * 32 + (mt << 4) + (quad << 2) + r;
                    hs[QOFF + (c >> 3) * 520 + (t << 3) + (c & 7)] = f2b(cq[mt][nt][r]);
                    hs[KOFF + (c >> 3) * 520 + (t << 3) + (c & 7)] = f2b(ck[mt][nt][r]);
                }
                const int key0 = mh * 32 + (mt << 4) + (quad << 2);   // r=0 key
                *(uint2*)(&hs[VTOFF + (key0 >> 3) * 264 + (c << 3) + (key0 & 7)]) =
                    pack4(cv[mt][nt][0], cv[mt][nt][1], cv[mt][nt][2], cv[mt][nt][3]);
            }
        __syncthreads();   // s1: q,k,vT of both halves visible to pair

        // ---- S^T = k q^T (full keys x own q-half), K=32 = hd ----
        s16x8 kf[4];
        #pragma unroll
        for (int mk = 0; mk < 4; ++mk) {
            V8 v; v.u4 = *(const uint4*)(&hs[KOFF + quad * 520 + (((mk << 4) + col) << 3)]);
            kf[mk] = v.h;
        }
        f32x4 ST[4][2];
        #pragma unroll
        for (int nqo = 0; nqo < 2; ++nqo) {
            const int nq = (mh << 1) | nqo;
            V8 v; v.u4 = *(const uint4*)(&hs[QOFF + quad * 520 + (((nq << 4) + col) << 3)]);
            #pragma unroll
            for (int mk = 0; mk < 4; ++mk)
                ST[mk][nqo] = mfma16(kf[mk], v.h, (f32x4){0.f, 0.f, 0.f, 0.f});
        }

        // ---- softmax: keys are in-lane (mk,r) x quads -> 15 fmax + 2 shfl ----
        const float smul = 0.17677669529663689f * 1.4426950408889634f;  // scale*log2e
        float inv[2];
        #pragma unroll
        for (int nqo = 0; nqo < 2; ++nqo) {
            float m0 = ST[0][nqo][0];
            #pragma unroll
            for (int mk = 0; mk < 4; ++mk)
                #pragma unroll
                for (int r = 0; r < 4; ++r) m0 = fmaxf(m0, ST[mk][nqo][r]);
            m0 = fmaxf(m0, __shfl_xor(m0, 16));
            m0 = fmaxf(m0, __shfl_xor(m0, 32));
            float s0 = 0.f;
            #pragma unroll
            for (int mk = 0; mk < 4; ++mk)
                #pragma unroll
                for (int r = 0; r < 4; ++r) {
                    const float pv = exp2f((ST[mk][nqo][r] - m0) * smul);
                    ST[mk][nqo][r] = pv; s0 += pv;
                }
            s0 += __shfl_xor(s0, 16);
            s0 += __shfl_xor(s0, 32);
            inv[nqo] = 1.0f / s0;        // deferred to O-scale
        }

        // ---- PV in two key-halves: O^T = vT . P  (P overlays q, own slots) ----
        f32x4 OT[2][2];
        #pragma unroll
        for (int dt = 0; dt < 2; ++dt)
            #pragma unroll
            for (int qto = 0; qto < 2; ++qto) OT[dt][qto] = (f32x4){0.f, 0.f, 0.f, 0.f};
        #pragma unroll
        for (int kh = 0; kh < 2; ++kh) {
            #pragma unroll
            for (int mk2 = 0; mk2 < 2; ++mk2) {
                const int mk = (kh << 1) | mk2;
                const int keyl0 = (mk2 << 4) + (quad << 2);   // key local to half
                #pragma unroll
                for (int nqo = 0; nqo < 2; ++nqo) {
                    const int q = ((((mh << 1) | nqo) << 4) + col);
                    *(uint2*)(&hs[QOFF + (keyl0 >> 3) * 520 + (q << 3) + (keyl0 & 7)]) =
                        pack4(ST[mk][nqo][0], ST[mk][nqo][1], ST[mk][nqo][2], ST[mk][nqo][3]);
                }
            }
            s16x8 vf[2];
            #pragma unroll
            for (int dt = 0; dt < 2; ++dt) {
                V8 v; v.u4 = *(const uint4*)(&hs[VTOFF + ((kh << 2) + quad) * 264 + (((dt << 4) + col) << 3)]);
                vf[dt] = v.h;
            }
            #pragma unroll
            for (int qto = 0; qto < 2; ++qto) {
                const int q = ((((mh << 1) | qto) << 4) + col);
                V8 pf; pf.u4 = *(const uint4*)(&hs[QOFF + quad * 520 + (q << 3)]);
                #pragma unroll
                for (int dt = 0; dt < 2; ++dt)
                    OT[dt][qto] = mfma16(vf[dt], pf.h, OT[dt][qto]);
            }
        }
        __syncthreads();   // s2: all PV reads done before ob overlays scratch

        // ---- o (scaled) -> ob [64 tok][128 ch], swizzled, b64-packed ----
        #pragma unroll
        for (int dt = 0; dt < 2; ++dt)
            #pragma unroll
            for (int qto = 0; qto < 2; ++qto) {
                const int t = ((((mh << 1) | qto) << 4) + col);
                const int ch0 = (pid << 5) + (dt << 4) + (quad << 2);
                const int c8p = ch0 >> 3;
                *(uint2*)(&ob[(t << 7) + ((c8p ^ (t & 7)) << 3) + (ch0 & 7)]) =
                    pack4(OT[dt][qto][0] * inv[qto], OT[dt][qto][1] * inv[qto],
                          OT[dt][qto][2] * inv[qto], OT[dt][qto][3] * inv[qto]);
            }
        __syncthreads();   // s3: ob complete

        // ---- proj partial: K-chunk = this pass's heads (kkg = p*4 + kkl) ----
        #pragma unroll 2
        for (int kkl = 0; kkl < 4; ++kkl) {
            const int kkg = (p << 2) | kkl;
            s16x8 a2[2];
            #pragma unroll
            for (int mt = 0; mt < 2; ++mt) {
                const int t = mh * 32 + (mt << 4) + col;
                const int c8p = (kkl << 2) | quad;
                V8 v; v.u4 = *(const uint4*)(&ob[(t << 7) + ((c8p ^ (t & 7)) << 3)]);
                a2[mt] = v.h;
            }
            #pragma unroll
            for (int nt = 0; nt < 8; ++nt) {
                s16x8 b;
                if constexpr (PK) {
                    const ushort* W = (const ushort*)Wp;
                    const size_t base = ((size_t)(((pid << 3) | nt) << 4) + kkg) * 512 + (lane << 3);
                    V8 v; v.u4 = *(const uint4*)(&W[base]); b = v.h;
                } else {
                    const float* W = (const float*)Wp;
                    V8 v; cvt8(W + (size_t)((pid << 7) + (nt << 4) + col) * 512 + (kkg << 5) + (quad << 3), v);
                    b = v.h;
                }
                #pragma unroll
                for (int mt = 0; mt < 2; ++mt)
                    pacc[mt][nt] = mfma16(a2[mt], b, pacc[mt][nt]);
            }
        }
        // no barrier here: next pass's GEMM1 only reads xw/weights; BAR(a)
        // before its scratch stores protects these proj reads.
    }

    // ---------------- epilogue: bias + fp32 out at merged positions ----------
    const size_t wbase = (size_t)(bb * 4096 + wh * 512 + ww * 8) * 512;
    #pragma unroll
    for (int nt = 0; nt < 8; ++nt) {
        const int cg = (pid << 7) + (nt << 4) + col;
        const float bias = bproj[cg];
        #pragma unroll
        for (int mt = 0; mt < 2; ++mt)
            #pragma unroll
            for (int r = 0; r < 4; ++r) {
                const int t = mh * 32 + (mt << 4) + (quad << 2) + r;
                const size_t go = wbase + (size_t)(((t >> 3) << 6) + (t & 7)) * 512;
                out[go + cg] = pacc[mt][nt][r] + bias;
            }
    }
}

extern "C" void kernel_launch(void* const* d_in, const int* in_sizes, int n_in,
                              void* d_out, int out_size, void* d_ws, size_t ws_size,
                              hipStream_t stream) {
    const float* x     = (const float*)d_in[0];
    const float* wqkv  = (const float*)d_in[1];
    const float* wproj = (const float*)d_in[2];
    const float* bproj = (const float*)d_in[3];
    float* out = (float*)d_out;
    (void)in_sizes; (void)n_in; (void)out_size;

    if (ws_size >= 2097152) {
        ushort* wpk = (ushort*)d_ws;
        pack_w<<<dim3(512), dim3(256), 0, stream>>>(wqkv, wproj, wpk);
        win_fused<true><<<dim3(1024), dim3(512), 0, stream>>>(
            x, wpk, wpk + 786432, bproj, out);
    } else {
        win_fused<false><<<dim3(1024), dim3(512), 0, stream>>>(
            x, wqkv, wproj, bproj, out);
    }
}